// Round 10
// baseline (58.438 us; speedup 1.0000x reference)
//
#include <hip/hip_runtime.h>

#define N_NODES 50000
#define N_EDGES 1250000
#define D 64
#define ALPHA 0.5f

#define NB 782            // ceil(50000 / 64) buckets of 64 nodes
#define BCAP 2048         // fixed region per bucket (mean 1600, +11 sigma)
#define GEMM_T 512        // nodes per gemm block (thread-per-node)
#define NGEMM 98          // ceil(N_NODES / GEMM_T)
#define P1_BATCH 8192     // edges per binning block
#define NBIN 153          // ceil(N_EDGES / P1_BATCH)

typedef __attribute__((ext_vector_type(8))) _Float16 half8;

// NOTE: macro parameter names must not collide with float4 members!
#define ACC8(A0, A1, hh, ww)                                            \
    A0.x += (ww) * (float)(hh)[0]; A0.y += (ww) * (float)(hh)[1];       \
    A0.z += (ww) * (float)(hh)[2]; A0.w += (ww) * (float)(hh)[3];       \
    A1.x += (ww) * (float)(hh)[4]; A1.y += (ww) * (float)(hh)[5];       \
    A1.z += (ww) * (float)(hh)[6]; A1.w += (ww) * (float)(hh)[7];

// ================= fast path =================

// init: zero bucket counters; build wt[k*64+o] = ALPHA * W[o][k]
__global__ void init_kernel(const float* __restrict__ W, float* __restrict__ wt,
                            int* __restrict__ gcur) {
    int t = threadIdx.x;
    for (int i = t; i < NB; i += 512) gcur[i] = 0;
    for (int i = t; i < D * D; i += 512) {
        int k = i >> 6;
        int o = i & 63;
        wt[i] = ALPHA * W[o * D + k];
    }
}

// Heterogeneous prep kernel:
//   blocks [0, NGEMM)        : g[n] = feature[n] @ wt  (fp16 out; wt pre-scaled)
//                              thread-per-node, W via wave-uniform loads (s_load)
//   blocks [NGEMM, +NBIN)    : bin edges -> fixed per-bucket regions,
//                              payload packed 4B: dlocal6|src16|q10(w)
__global__ __launch_bounds__(512)
void prep_kernel(const float* __restrict__ feature, const float* __restrict__ wt,
                 const int* __restrict__ src, const int* __restrict__ dst,
                 const float* __restrict__ ew,
                 _Float16* __restrict__ g,
                 int* __restrict__ gcur, unsigned* __restrict__ binned) {
    __shared__ int hist[NB];
    __shared__ int gbase[NB];
    __shared__ int cur[NB];
    int t = threadIdx.x;

    if (blockIdx.x < NGEMM) {
        // ---------- GEMM: one thread per node, acc in VGPRs ----------
        int node = blockIdx.x * GEMM_T + t;
        if (node < N_NODES) {
            const float4* frow = (const float4*)(feature + (size_t)node * D);
            float4 acc4[16];
            #pragma unroll
            for (int m = 0; m < 16; ++m) acc4[m] = make_float4(0.f, 0.f, 0.f, 0.f);

            #pragma unroll 1
            for (int kc = 0; kc < 16; ++kc) {
                float4 h = frow[kc];                    // 4 input dims
                const float* wr = wt + (kc << 8);       // 4 k-rows of 64 (uniform)
                #pragma unroll
                for (int kk = 0; kk < 4; ++kk) {
                    float fv = (kk == 0) ? h.x : (kk == 1) ? h.y : (kk == 2) ? h.z : h.w;
                    const float4* wp = (const float4*)(wr + (kk << 6));
                    #pragma unroll
                    for (int m = 0; m < 16; ++m) {
                        float4 wv = wp[m];
                        acc4[m].x += fv * wv.x;
                        acc4[m].y += fv * wv.y;
                        acc4[m].z += fv * wv.z;
                        acc4[m].w += fv * wv.w;
                    }
                }
            }

            half8* gp = (half8*)(g + (size_t)node * D);
            #pragma unroll
            for (int m = 0; m < 8; ++m) {
                float4 lo = acc4[2 * m];
                float4 hi = acc4[2 * m + 1];
                half8 hv;
                hv[0] = (_Float16)lo.x; hv[1] = (_Float16)lo.y;
                hv[2] = (_Float16)lo.z; hv[3] = (_Float16)lo.w;
                hv[4] = (_Float16)hi.x; hv[5] = (_Float16)hi.y;
                hv[6] = (_Float16)hi.z; hv[7] = (_Float16)hi.w;
                gp[m] = hv;
            }
        }
    } else {
        // ---------- binning: 8192 edges, 512 threads ----------
        for (int i = t; i < NB; i += 512) { hist[i] = 0; cur[i] = 0; }
        __syncthreads();

        int base = (blockIdx.x - NGEMM) * P1_BATCH;
        unsigned pay[16];
        short bks[16];
        #pragma unroll
        for (int k = 0; k < 16; ++k) {
            int j = base + t + 512 * k;
            bks[k] = -1;
            if (j < N_EDGES) {
                int d = dst[j];
                int s = src[j];
                float w = 1.0f - ew[j];
                int q = (int)(w * 1024.f + 0.5f);
                if (q > 1023) q = 1023;
                pay[k] = ((unsigned)(d & 63) << 26) | ((unsigned)s << 10) | (unsigned)q;
                int bk = d >> 6;
                bks[k] = (short)bk;
                atomicAdd(&hist[bk], 1);
            }
        }
        __syncthreads();
        for (int i = t; i < NB; i += 512) {
            int c = hist[i];
            if (c) gbase[i] = atomicAdd(&gcur[i], c);
        }
        __syncthreads();
        #pragma unroll
        for (int k = 0; k < 16; ++k) {
            if (bks[k] >= 0) {
                int bk = bks[k];
                int r2 = atomicAdd(&cur[bk], 1);
                int p = gbase[bk] + r2;
                if (p < BCAP) binned[(size_t)bk * BCAP + p] = pay[k];
            }
        }
    }
}

// pass2: one block per bucket. LDS counting sort by node, then gather all 64
// dims: 16 slots x 32 lanes; per slot 4 edge-groups x 8 lanes; each lane loads
// half8 (16B) so 8 lanes cover a full 128B g row. 4-deep ILP on the edge loop.
__global__ __launch_bounds__(512)
void bucket_gather_kernel(const _Float16* __restrict__ g,
                          const int* __restrict__ gcur,
                          const unsigned* __restrict__ binned,
                          const float* __restrict__ bias,
                          float* __restrict__ out) {
    __shared__ unsigned sorted[BCAP];    // 8 KB
    __shared__ int nhist[64];
    __shared__ int noff[65];
    __shared__ int ncur[64];
    int t = threadIdx.x;
    int bk = blockIdx.x;
    int cnt = gcur[bk];
    if (cnt > BCAP) cnt = BCAP;
    size_t base = (size_t)bk * BCAP;

    if (t < 64) nhist[t] = 0;
    __syncthreads();

    unsigned st[4];
    #pragma unroll
    for (int k = 0; k < 4; ++k) {
        int i = t + 512 * k;
        if (i < cnt) {
            unsigned p = binned[base + i];
            st[k] = p;
            atomicAdd(&nhist[p >> 26], 1);
        }
    }
    __syncthreads();
    if (t < 64) {                 // wave 0: 64-lane shuffle scan
        int v = nhist[t];
        int incl = v;
        #pragma unroll
        for (int off = 1; off < 64; off <<= 1) {
            int x = __shfl_up(incl, off);
            if (t >= off) incl += x;
        }
        noff[t] = incl - v;
        ncur[t] = incl - v;
        if (t == 63) noff[64] = incl;
    }
    __syncthreads();
    #pragma unroll
    for (int k = 0; k < 4; ++k) {
        int i = t + 512 * k;
        if (i < cnt) {
            int nl = st[k] >> 26;
            int pos = atomicAdd(&ncur[nl], 1);
            sorted[pos] = st[k];
        }
    }
    __syncthreads();

    // gather
    int slot  = t >> 5;        // 0..15
    int grp   = (t >> 3) & 3;  // edge group within slot
    int lane8 = t & 7;         // dim chunk: dims lane8*8 .. +8
    float4 bb0 = ((const float4*)bias)[lane8 * 2];
    float4 bb1 = ((const float4*)bias)[lane8 * 2 + 1];

    #pragma unroll
    for (int rep = 0; rep < 4; ++rep) {
        int nn = slot + rep * 16;
        int node = (bk << 6) + nn;
        if (node >= N_NODES) continue;
        int beg = noff[nn];
        int end = noff[nn + 1];

        float4 a0 = make_float4(0.f, 0.f, 0.f, 0.f);
        float4 a1 = make_float4(0.f, 0.f, 0.f, 0.f);
        float4 c0 = make_float4(0.f, 0.f, 0.f, 0.f);
        float4 c1 = make_float4(0.f, 0.f, 0.f, 0.f);
        float4 d0 = make_float4(0.f, 0.f, 0.f, 0.f);
        float4 d1 = make_float4(0.f, 0.f, 0.f, 0.f);
        float4 e0 = make_float4(0.f, 0.f, 0.f, 0.f);
        float4 e1 = make_float4(0.f, 0.f, 0.f, 0.f);

        int j = beg + grp;
        for (; j + 12 < end; j += 16) {        // 4 edges in flight per group
            unsigned p0 = sorted[j];
            unsigned p1 = sorted[j + 4];
            unsigned p2 = sorted[j + 8];
            unsigned p3 = sorted[j + 12];
            half8 h0 = ((const half8*)(g + (size_t)((p0 >> 10) & 0xFFFFu) * D))[lane8];
            half8 h1 = ((const half8*)(g + (size_t)((p1 >> 10) & 0xFFFFu) * D))[lane8];
            half8 h2 = ((const half8*)(g + (size_t)((p2 >> 10) & 0xFFFFu) * D))[lane8];
            half8 h3 = ((const half8*)(g + (size_t)((p3 >> 10) & 0xFFFFu) * D))[lane8];
            float w0 = (float)(p0 & 1023u) * (1.0f / 1024.0f);
            float w1 = (float)(p1 & 1023u) * (1.0f / 1024.0f);
            float w2 = (float)(p2 & 1023u) * (1.0f / 1024.0f);
            float w3 = (float)(p3 & 1023u) * (1.0f / 1024.0f);
            ACC8(a0, a1, h0, w0);
            ACC8(c0, c1, h1, w1);
            ACC8(d0, d1, h2, w2);
            ACC8(e0, e1, h3, w3);
        }
        for (; j + 4 < end; j += 8) {          // 2 edges in flight
            unsigned p0 = sorted[j];
            unsigned p1 = sorted[j + 4];
            half8 h0 = ((const half8*)(g + (size_t)((p0 >> 10) & 0xFFFFu) * D))[lane8];
            half8 h1 = ((const half8*)(g + (size_t)((p1 >> 10) & 0xFFFFu) * D))[lane8];
            float w0 = (float)(p0 & 1023u) * (1.0f / 1024.0f);
            float w1 = (float)(p1 & 1023u) * (1.0f / 1024.0f);
            ACC8(a0, a1, h0, w0);
            ACC8(c0, c1, h1, w1);
        }
        for (; j < end; j += 4) {              // tail
            unsigned p0 = sorted[j];
            half8 h0 = ((const half8*)(g + (size_t)((p0 >> 10) & 0xFFFFu) * D))[lane8];
            float w0 = (float)(p0 & 1023u) * (1.0f / 1024.0f);
            ACC8(a0, a1, h0, w0);
        }
        a0.x += c0.x + d0.x + e0.x; a0.y += c0.y + d0.y + e0.y;
        a0.z += c0.z + d0.z + e0.z; a0.w += c0.w + d0.w + e0.w;
        a1.x += c1.x + d1.x + e1.x; a1.y += c1.y + d1.y + e1.y;
        a1.z += c1.z + d1.z + e1.z; a1.w += c1.w + d1.w + e1.w;

        // reduce across the 4 edge-groups (thread-id bits 3 and 4)
        a0.x += __shfl_xor(a0.x, 8);  a0.y += __shfl_xor(a0.y, 8);
        a0.z += __shfl_xor(a0.z, 8);  a0.w += __shfl_xor(a0.w, 8);
        a1.x += __shfl_xor(a1.x, 8);  a1.y += __shfl_xor(a1.y, 8);
        a1.z += __shfl_xor(a1.z, 8);  a1.w += __shfl_xor(a1.w, 8);
        a0.x += __shfl_xor(a0.x, 16); a0.y += __shfl_xor(a0.y, 16);
        a0.z += __shfl_xor(a0.z, 16); a0.w += __shfl_xor(a0.w, 16);
        a1.x += __shfl_xor(a1.x, 16); a1.y += __shfl_xor(a1.y, 16);
        a1.z += __shfl_xor(a1.z, 16); a1.w += __shfl_xor(a1.w, 16);

        if (grp == 0) {
            float4 r0, r1;
            r0.x = a0.x + ALPHA * bb0.x; r0.y = a0.y + ALPHA * bb0.y;
            r0.z = a0.z + ALPHA * bb0.z; r0.w = a0.w + ALPHA * bb0.w;
            r1.x = a1.x + ALPHA * bb1.x; r1.y = a1.y + ALPHA * bb1.y;
            r1.z = a1.z + ALPHA * bb1.z; r1.w = a1.w + ALPHA * bb1.w;
            float4* op = (float4*)(out + (size_t)node * D + lane8 * 8);
            op[0] = r0;
            op[1] = r1;
        }
    }
}

// ================= fallback path (atomic scatter, fp32) =================

__global__ void init_out_kernel(float* __restrict__ out) {
    int i = blockIdx.x * 256 + threadIdx.x;
    const int total4 = N_NODES * D / 4;
    if (i < total4) ((float4*)out)[i] = make_float4(0.f, 0.f, 0.f, 0.f);
}

__global__ void scatter_kernel(const float* __restrict__ feature,
                               const float* __restrict__ ew,
                               const int* __restrict__ src,
                               const int* __restrict__ dst,
                               float* __restrict__ out) {
    long long tid = (long long)blockIdx.x * 256 + threadIdx.x;
    int e = (int)(tid >> 4);
    int l = (int)(tid & 15);
    if (e >= N_EDGES) return;
    int s = src[e];
    int d = dst[e];
    float w = 1.0f - ew[e];
    float4 v = ((const float4*)(feature + (size_t)s * D))[l];
    float* op = out + (size_t)d * D + l * 4;
    atomicAdd(op + 0, v.x * w);
    atomicAdd(op + 1, v.y * w);
    atomicAdd(op + 2, v.z * w);
    atomicAdd(op + 3, v.w * w);
}

__global__ void linear_kernel(const float* __restrict__ W,
                              const float* __restrict__ b,
                              float* __restrict__ out) {
    __shared__ float Wl[D * D];
    __shared__ float bl[D];
    int t = threadIdx.x;
    for (int i = t; i < D * D / 4; i += 256)
        ((float4*)Wl)[i] = ((const float4*)W)[i];
    if (t < D) bl[t] = b[t];
    __syncthreads();

    int n = blockIdx.x * 256 + t;
    if (n >= N_NODES) return;

    float4 h[16];
    float4* row = (float4*)(out + (size_t)n * D);
    #pragma unroll
    for (int i = 0; i < 16; ++i) h[i] = row[i];

    #pragma unroll 1
    for (int o = 0; o < D; o += 4) {
        float4 accv;
        float* accp = &accv.x;
        #pragma unroll
        for (int oo = 0; oo < 4; ++oo) {
            const float4* wr = (const float4*)(Wl + (o + oo) * D);
            float acc = 0.f;
            #pragma unroll
            for (int k = 0; k < 16; ++k) {
                float4 wv = wr[k];
                acc += h[k].x * wv.x + h[k].y * wv.y + h[k].z * wv.z + h[k].w * wv.w;
            }
            accp[oo] = ALPHA * (acc + bl[o + oo]);
        }
        row[o / 4] = accv;
    }
}

// ================= launch =================

extern "C" void kernel_launch(void* const* d_in, const int* in_sizes, int n_in,
                              void* d_out, int out_size, void* d_ws, size_t ws_size,
                              hipStream_t stream) {
    const float* feature = (const float*)d_in[0];
    const float* ew      = (const float*)d_in[1];
    const float* W       = (const float*)d_in[2];
    const float* b       = (const float*)d_in[3];
    const int*   src     = (const int*)d_in[4];
    const int*   dst     = (const int*)d_in[5];
    float* out = (float*)d_out;

    // scratch: g fp16 [N*D], binned u32 [NB*BCAP], gcur [NB], wt f32 [D*D]
    const size_t g_bytes      = (size_t)N_NODES * D * 2;       // 6.4 MB
    const size_t binned_bytes = (size_t)NB * BCAP * 4;         // 6.4 MB
    const size_t need = g_bytes + binned_bytes + sizeof(int) * NB
                        + sizeof(float) * D * D;

    if (ws_size >= need) {
        _Float16* g      = (_Float16*)d_ws;
        unsigned* binned = (unsigned*)((char*)d_ws + g_bytes);
        int* gcur        = (int*)((char*)d_ws + g_bytes + binned_bytes);
        float* wt        = (float*)((char*)d_ws + g_bytes + binned_bytes
                                    + sizeof(int) * NB);

        init_kernel<<<1, 512, 0, stream>>>(W, wt, gcur);
        prep_kernel<<<NGEMM + NBIN, 512, 0, stream>>>(feature, wt, src, dst, ew,
                                                      g, gcur, binned);
        bucket_gather_kernel<<<NB, 512, 0, stream>>>(g, gcur, binned, b, out);
    } else {
        init_out_kernel<<<(N_NODES * D / 4 + 255) / 256, 256, 0, stream>>>(out);
        {
            long long threads = (long long)N_EDGES * 16;
            int blocks = (int)((threads + 255) / 256);
            scatter_kernel<<<blocks, 256, 0, stream>>>(feature, ew, src, dst, out);
        }
        linear_kernel<<<(N_NODES + 255) / 256, 256, 0, stream>>>(W, b, out);
    }
}